// Round 4
// baseline (1187.551 us; speedup 1.0000x reference)
//
#include <hip/hip_runtime.h>
#include <hip/hip_bf16.h>
#include <math.h>

namespace {

constexpr int C = 128;       // channels
constexpr int K = 32;        // max degree
constexpr int TILE_M = 128;  // GEMM row tile
constexpr int LDSW = 132;    // LDS row stride in floats (128 + 4 pad)
constexpr int NSLICE = 8;    // channel slices == XCD count
constexpr int SLICE_C = 16;  // channels per slice (32 B bf16 rows)
constexpr int CHUNK = 32;    // nodes per gather work item

typedef int int4v __attribute__((ext_vector_type(4)));
typedef float float2v __attribute__((ext_vector_type(2)));

__device__ __forceinline__ float bf2f(unsigned short u) {
    return __uint_as_float(((unsigned int)u) << 16);
}

__device__ __forceinline__ int xcc_id() {
    unsigned x;
    asm("s_getreg_b32 %0, hwreg(HW_REG_XCC_ID)" : "=s"(x));
    return (int)(x & (NSLICE - 1));
}

// ---------------------------------------------------------------------------
// Kernel 0: invs[n] = 1/sqrt(1 + #valid neighbors); also zero the 16 work
// counters (block 0).
// ---------------------------------------------------------------------------
__global__ __launch_bounds__(256) void deg_kernel(const int* __restrict__ edge,
                                                  float* __restrict__ invs,
                                                  int* __restrict__ cnt, int N) {
    if (blockIdx.x == 0 && threadIdx.x < 2 * NSLICE) cnt[threadIdx.x] = 0;
    int t = threadIdx.x;
    int node = blockIdx.x * 8 + (t >> 5);
    int k = t & 31;
    int e = (node < N) ? edge[(size_t)node * K + k] : -1;
    unsigned long long m = __ballot(e >= 0);
    int lane = t & 63;
    unsigned int half = (lane < 32) ? (unsigned int)(m & 0xffffffffULL)
                                    : (unsigned int)(m >> 32);
    int c = __popc(half);
    if (k == 0 && node < N) invs[node] = 1.0f / sqrtf((float)(c + 1));
}

// ---------------------------------------------------------------------------
// Kernel 1: H[slice][n][c'] = bf16( (X[n] . W[ch]) * invs[n] ),  ch=16*slice+c'
// fp32 vector-ALU GEMM, W in LDS (67.6 KB -> 2 blocks/CU), X read from global
// with a software-pipelined register prefetch (hide L2/HBM latency).
// Input layout: canonical [N][C] (SLICED_IN=false) or slice-major [8][N][16]
// fp32 (SLICED_IN=true, for the layer-1 activation).
// ---------------------------------------------------------------------------
template <bool SLICED_IN>
__global__ __launch_bounds__(256) void gemm_scale_kernel(
    const float* __restrict__ X, const float* __restrict__ W,
    const float* __restrict__ invs, unsigned short* __restrict__ H, int N) {
    __shared__ float Ws[C * LDSW];

    const int t = threadIdx.x;
    const int n0 = blockIdx.x * TILE_M;
    const size_t sstride = (size_t)N * SLICE_C;  // elements per slice region

    for (int p = t; p < C * C / 4; p += 256) {
        int row = p >> 5;
        int c4 = p & 31;
        float4 v = ((const float4*)W)[p];
        *(float4*)&Ws[row * LDSW + c4 * 4] = v;
    }
    __syncthreads();

    const int tx = t & 15;  // col base: cols tx + 16*c
    const int ty = t >> 4;  // row base: rows ty + 16*r

    const float* xbase[8];
#pragma unroll
    for (int r = 0; r < 8; ++r) {
        int n = n0 + ty + r * 16;
        if (n > N - 1) n = N - 1;  // clamp; writes are guarded
        xbase[r] = X + (SLICED_IN ? (size_t)n * SLICE_C : (size_t)n * C);
    }

    float acc[8][8];
#pragma unroll
    for (int r = 0; r < 8; ++r)
#pragma unroll
        for (int c = 0; c < 8; ++c) acc[r][c] = 0.f;

    float4 a[8], an[8];
#pragma unroll
    for (int r = 0; r < 8; ++r)
        an[r] = *(const float4*)(xbase[r]);  // i=0 chunk (offset 0 both layouts)

#pragma unroll 4
    for (int i = 0; i < C; i += 4) {
#pragma unroll
        for (int r = 0; r < 8; ++r) a[r] = an[r];
        int i4 = i + 4;
        if (i4 < C) {
            size_t off = SLICED_IN ? ((size_t)(i4 >> 4) * sstride + (i4 & 12))
                                   : (size_t)i4;
#pragma unroll
            for (int r = 0; r < 8; ++r)
                an[r] = *(const float4*)(xbase[r] + off);
        }
        float4 b[8];
#pragma unroll
        for (int c = 0; c < 8; ++c)
            b[c] = *(const float4*)&Ws[(tx + c * 16) * LDSW + i];
#pragma unroll
        for (int r = 0; r < 8; ++r)
#pragma unroll
            for (int c = 0; c < 8; ++c) {
                acc[r][c] += a[r].x * b[c].x;
                acc[r][c] += a[r].y * b[c].y;
                acc[r][c] += a[r].z * b[c].z;
                acc[r][c] += a[r].w * b[c].w;
            }
    }

    // Epilogue: slice-major bf16 output. col = tx + 16*c -> slice c, offset tx.
#pragma unroll
    for (int r = 0; r < 8; ++r) {
        int n = n0 + ty + r * 16;
        if (n < N) {
            float s = invs[n];
#pragma unroll
            for (int c = 0; c < 8; ++c) {
                __hip_bfloat16 hv = __float2bfloat16(acc[r][c] * s);
                H[(size_t)c * sstride + (size_t)n * SLICE_C + tx] =
                    *(unsigned short*)&hv;
            }
        }
    }
}

// ---------------------------------------------------------------------------
// Kernel 2: channel-sliced gather + ELU with XCD-pinned slices.
// H is slice-major [8][N][16] bf16; slice s (3.2 MB) stays resident in XCD
// s's private L2. Each block reads its XCC_ID and drains the work queue of
// its own slice first, then steals from other slices (correctness does not
// depend on the XCD mapping). Edge loads and output stores are nontemporal
// so they don't evict the L2-resident slice.
// 8 lanes per node (ushort2 = 2 channels/lane), 32 nodes per chunk.
// ---------------------------------------------------------------------------
template <bool CANON_OUT>
__global__ __launch_bounds__(256) void gather_elu_kernel(
    const unsigned short* __restrict__ H, const int* __restrict__ edge,
    const float* __restrict__ invs, float* __restrict__ out, int N,
    int* __restrict__ cnt) {
    __shared__ __align__(16) int idx_s[CHUNK][36];  // stride 36: conflict-free
    __shared__ int cur_chunk;

    const int t = threadIdx.x;
    const int nchunks = (N + CHUNK - 1) / CHUNK;
    const size_t sstride = (size_t)N * SLICE_C;
    const int myxcd = xcc_id();

    for (int soff = 0; soff < NSLICE; ++soff) {
        const int s = (myxcd + soff) & (NSLICE - 1);
        const unsigned short* hs = H + (size_t)s * sstride;
        for (;;) {
            if (t == 0) cur_chunk = atomicAdd(&cnt[s], 1);
            __syncthreads();
            const int chunk = cur_chunk;
            if (chunk >= nchunks) break;  // uniform
            const int n0 = chunk * CHUNK;

            // Stage this chunk's edge lists (4 KB), nontemporal.
            {
                int p = t * 4;        // flat index into CHUNK*K
                int nl = p >> 5;      // K == 32
                int node = n0 + nl;
                int4v e = {-1, -1, -1, -1};
                if (node < N)
                    e = __builtin_nontemporal_load(
                        (const int4v*)(edge + (size_t)node * K + (p & 31)));
                *(int4v*)&idx_s[nl][p & 31] = e;
            }
            __syncthreads();

            const int nl = t >> 3;
            const int sub = t & 7;
            const int node = n0 + nl;
            if (node < N) {
                float a0 = 0.f, a1 = 0.f;
#pragma unroll
                for (int k = 0; k < K; ++k) {
                    int j = idx_s[nl][k];
                    if (j >= 0) {
                        ushort2 v = *(const ushort2*)(hs + (size_t)j * SLICE_C +
                                                      sub * 2);
                        a0 += bf2f(v.x);
                        a1 += bf2f(v.y);
                    }
                }
                ushort2 sv =
                    *(const ushort2*)(hs + (size_t)node * SLICE_C + sub * 2);
                float sc = invs[node];
                float r0 = (a0 + bf2f(sv.x)) * sc;
                float r1 = (a1 + bf2f(sv.y)) * sc;
                r0 = r0 > 0.f ? r0 : expm1f(r0);
                r1 = r1 > 0.f ? r1 : expm1f(r1);
                float2v rv = {r0, r1};
                float* dst = CANON_OUT
                                 ? (out + (size_t)node * C + s * SLICE_C + sub * 2)
                                 : (out + (size_t)s * sstride +
                                    (size_t)node * SLICE_C + sub * 2);
                __builtin_nontemporal_store(rv, (float2v*)dst);
            }
            __syncthreads();  // idx_s reads done before next staging
        }
    }
}

}  // namespace

extern "C" void kernel_launch(void* const* d_in, const int* in_sizes, int n_in,
                              void* d_out, int out_size, void* d_ws, size_t ws_size,
                              hipStream_t stream) {
    const float* x = (const float*)d_in[0];
    const int* edge = (const int*)d_in[1];
    const float* W1 = (const float*)d_in[2];
    const float* W2 = (const float*)d_in[3];
    float* out = (float*)d_out;
    const int N = in_sizes[0] / C;  // 100000

    // Workspace: cnt[16] | invs [N floats] | h [N*C bf16, slice-major]
    char* ws = (char*)d_ws;
    int* cnt = (int*)ws;
    float* invs = (float*)(ws + 256);
    size_t invs_bytes = ((size_t)N * sizeof(float) + 255) & ~(size_t)255;
    unsigned short* h = (unsigned short*)(ws + 256 + invs_bytes);

    const int nodeBlocks = (N + 7) / 8;
    const int gemmBlocks = (N + TILE_M - 1) / TILE_M;
    const int gatherBlocks = 2048;  // 8/CU, multiple of 8 XCDs

    deg_kernel<<<nodeBlocks, 256, 0, stream>>>(edge, invs, cnt, N);
    // Layer 1: x (canonical) -> h (sliced bf16) -> act (sliced fp32, in d_out)
    gemm_scale_kernel<false><<<gemmBlocks, 256, 0, stream>>>(x, W1, invs, h, N);
    gather_elu_kernel<false><<<gatherBlocks, 256, 0, stream>>>(h, edge, invs, out,
                                                               N, cnt);
    // Layer 2: act (sliced, d_out) -> h (sliced bf16) -> out (canonical, d_out)
    gemm_scale_kernel<true><<<gemmBlocks, 256, 0, stream>>>(out, W2, invs, h, N);
    gather_elu_kernel<true><<<gatherBlocks, 256, 0, stream>>>(h, edge, invs, out,
                                                              N, cnt + NSLICE);
}

// Round 5
// 474.696 us; speedup vs baseline: 2.5017x; 2.5017x over previous
//
#include <hip/hip_runtime.h>
#include <hip/hip_bf16.h>
#include <math.h>

namespace {

constexpr int C = 128;       // channels
constexpr int K = 32;        // max degree
constexpr int TILE_M = 128;  // GEMM row tile
constexpr int LDSW = 132;    // LDS row stride in floats (128 + 4 pad)
constexpr int NSLICE = 8;    // channel slices == XCD count
constexpr int SLICE_C = 16;  // channels per slice (32 B bf16 rows)
constexpr int NT = 128;      // nodes per gather tile

typedef int int4v __attribute__((ext_vector_type(4)));
typedef float float4v __attribute__((ext_vector_type(4)));
typedef unsigned short ushort8v __attribute__((ext_vector_type(8)));

__device__ __forceinline__ float bf2f(unsigned short u) {
    return __uint_as_float(((unsigned int)u) << 16);
}

// ---------------------------------------------------------------------------
// Kernel 0: invs[n] = 1/sqrt(1 + #valid neighbors)
// ---------------------------------------------------------------------------
__global__ __launch_bounds__(256) void deg_kernel(const int* __restrict__ edge,
                                                  float* __restrict__ invs, int N) {
    int t = threadIdx.x;
    int node = blockIdx.x * 8 + (t >> 5);
    int k = t & 31;
    int e = (node < N) ? edge[(size_t)node * K + k] : -1;
    unsigned long long m = __ballot(e >= 0);
    int lane = t & 63;
    unsigned int half = (lane < 32) ? (unsigned int)(m & 0xffffffffULL)
                                    : (unsigned int)(m >> 32);
    int c = __popc(half);
    if (k == 0 && node < N) invs[node] = 1.0f / sqrtf((float)(c + 1));
}

// ---------------------------------------------------------------------------
// Kernel 1: H[slice][n][c'] = bf16( (X[n] . W[ch]) * invs[n] ),  ch=16*slice+c'
// fp32 vector-ALU GEMM, W in LDS (67.6 KB -> 2 blocks/CU), X from global with
// a 1-deep register prefetch. UNCHANGED from round 4 (isolating gather fix).
// ---------------------------------------------------------------------------
template <bool SLICED_IN>
__global__ __launch_bounds__(256) void gemm_scale_kernel(
    const float* __restrict__ X, const float* __restrict__ W,
    const float* __restrict__ invs, unsigned short* __restrict__ H, int N) {
    __shared__ float Ws[C * LDSW];

    const int t = threadIdx.x;
    const int n0 = blockIdx.x * TILE_M;
    const size_t sstride = (size_t)N * SLICE_C;  // elements per slice region

    for (int p = t; p < C * C / 4; p += 256) {
        int row = p >> 5;
        int c4 = p & 31;
        float4 v = ((const float4*)W)[p];
        *(float4*)&Ws[row * LDSW + c4 * 4] = v;
    }
    __syncthreads();

    const int tx = t & 15;  // col base: cols tx + 16*c
    const int ty = t >> 4;  // row base: rows ty + 16*r

    const float* xbase[8];
#pragma unroll
    for (int r = 0; r < 8; ++r) {
        int n = n0 + ty + r * 16;
        if (n > N - 1) n = N - 1;  // clamp; writes are guarded
        xbase[r] = X + (SLICED_IN ? (size_t)n * SLICE_C : (size_t)n * C);
    }

    float acc[8][8];
#pragma unroll
    for (int r = 0; r < 8; ++r)
#pragma unroll
        for (int c = 0; c < 8; ++c) acc[r][c] = 0.f;

    float4 a[8], an[8];
#pragma unroll
    for (int r = 0; r < 8; ++r)
        an[r] = *(const float4*)(xbase[r]);

#pragma unroll 4
    for (int i = 0; i < C; i += 4) {
#pragma unroll
        for (int r = 0; r < 8; ++r) a[r] = an[r];
        int i4 = i + 4;
        if (i4 < C) {
            size_t off = SLICED_IN ? ((size_t)(i4 >> 4) * sstride + (i4 & 12))
                                   : (size_t)i4;
#pragma unroll
            for (int r = 0; r < 8; ++r)
                an[r] = *(const float4*)(xbase[r] + off);
        }
        float4 b[8];
#pragma unroll
        for (int c = 0; c < 8; ++c)
            b[c] = *(const float4*)&Ws[(tx + c * 16) * LDSW + i];
#pragma unroll
        for (int r = 0; r < 8; ++r)
#pragma unroll
            for (int c = 0; c < 8; ++c) {
                acc[r][c] += a[r].x * b[c].x;
                acc[r][c] += a[r].y * b[c].y;
                acc[r][c] += a[r].z * b[c].z;
                acc[r][c] += a[r].w * b[c].w;
            }
    }

    // Epilogue: slice-major bf16 output. col = tx + 16*c -> slice c, offset tx.
#pragma unroll
    for (int r = 0; r < 8; ++r) {
        int n = n0 + ty + r * 16;
        if (n < N) {
            float s = invs[n];
#pragma unroll
            for (int c = 0; c < 8; ++c) {
                __hip_bfloat16 hv = __float2bfloat16(acc[r][c] * s);
                H[(size_t)c * sstride + (size_t)n * SLICE_C + tx] =
                    *(unsigned short*)&hv;
            }
        }
    }
}

// ---------------------------------------------------------------------------
// Kernel 2: channel-sliced gather + ELU, STATIC work split (no atomics).
// slice = blockIdx & 7: round-robin dispatch keeps each slice's 256 blocks on
// one XCD, so the 3.2 MB bf16 slice stays resident in that XCD's private L2
// (round-4 FETCH_SIZE confirmed residency; the atomic queue was the cost).
// 2 lanes/node (ushort8 = 16 B dwordx4), 128-node tiles, [128][33] LDS edge
// staging (conflict-free reads: bank = (nl+k) & 31).
// ---------------------------------------------------------------------------
template <bool CANON_OUT>
__global__ __launch_bounds__(256) void gather_elu_kernel(
    const unsigned short* __restrict__ H, const int* __restrict__ edge,
    const float* __restrict__ invs, float* __restrict__ out, int N) {
    __shared__ int idx_s[NT][33];

    const int t = threadIdx.x;
    const int s = blockIdx.x & (NSLICE - 1);
    const int grp = blockIdx.x >> 3;
    const int ngrp = 256;
    const int ntiles = (N + NT - 1) / NT;
    const size_t sstride = (size_t)N * SLICE_C;
    const unsigned short* hs = H + (size_t)s * sstride;
    const int nl = t >> 1;
    const int half = t & 1;

    for (int tt = grp; tt < ntiles; tt += ngrp) {
        const int base = tt * NT;

        // Stage 128 nodes' edge lists (16 KB): 4 x int4 per thread, coalesced
        // global reads, nontemporal so they don't evict the L2-pinned slice.
#pragma unroll
        for (int ii = 0; ii < 4; ++ii) {
            int p = (ii * 256 + t) * 4;  // flat int index into NT*K
            int r = p >> 5;              // K == 32
            int c0 = p & 31;
            int node = base + r;
            int4v e = {-1, -1, -1, -1};
            if (node < N)
                e = __builtin_nontemporal_load(
                    (const int4v*)(edge + (size_t)node * K + c0));
            idx_s[r][c0 + 0] = e.x;
            idx_s[r][c0 + 1] = e.y;
            idx_s[r][c0 + 2] = e.z;
            idx_s[r][c0 + 3] = e.w;
        }
        __syncthreads();

        const int node = base + nl;
        if (node < N) {
            const unsigned short* hh = hs + half * 8;
            float acc[8];
#pragma unroll
            for (int i = 0; i < 8; ++i) acc[i] = 0.f;
#pragma unroll
            for (int k = 0; k < K; ++k) {
                int j = idx_s[nl][k];
                if (j >= 0) {
                    ushort8v v = *(const ushort8v*)(hh + (size_t)j * SLICE_C);
#pragma unroll
                    for (int i = 0; i < 8; ++i) acc[i] += bf2f(v[i]);
                }
            }
            ushort8v sv = *(const ushort8v*)(hh + (size_t)node * SLICE_C);
            float sc = invs[node];
            float r[8];
#pragma unroll
            for (int i = 0; i < 8; ++i) {
                float x = (acc[i] + bf2f(sv[i])) * sc;
                r[i] = x > 0.f ? x : expm1f(x);
            }
            float* dst = CANON_OUT
                             ? (out + (size_t)node * C + s * SLICE_C + half * 8)
                             : (out + (size_t)s * sstride +
                                (size_t)node * SLICE_C + half * 8);
            float4v lo = {r[0], r[1], r[2], r[3]};
            float4v hi = {r[4], r[5], r[6], r[7]};
            __builtin_nontemporal_store(lo, (float4v*)dst);
            __builtin_nontemporal_store(hi, (float4v*)(dst + 4));
        }
        __syncthreads();  // idx_s reads done before next tile's staging
    }
}

}  // namespace

extern "C" void kernel_launch(void* const* d_in, const int* in_sizes, int n_in,
                              void* d_out, int out_size, void* d_ws, size_t ws_size,
                              hipStream_t stream) {
    const float* x = (const float*)d_in[0];
    const int* edge = (const int*)d_in[1];
    const float* W1 = (const float*)d_in[2];
    const float* W2 = (const float*)d_in[3];
    float* out = (float*)d_out;
    const int N = in_sizes[0] / C;  // 100000

    // Workspace: invs [N floats] | h [N*C bf16, slice-major]
    char* ws = (char*)d_ws;
    float* invs = (float*)ws;
    size_t invs_bytes = ((size_t)N * sizeof(float) + 255) & ~(size_t)255;
    unsigned short* h = (unsigned short*)(ws + invs_bytes);

    const int nodeBlocks = (N + 7) / 8;
    const int gemmBlocks = (N + TILE_M - 1) / TILE_M;
    const int gatherBlocks = 2048;  // 256 groups x 8 slices

    deg_kernel<<<nodeBlocks, 256, 0, stream>>>(edge, invs, N);
    // Layer 1: x (canonical) -> h (sliced bf16) -> act (sliced fp32, in d_out)
    gemm_scale_kernel<false><<<gemmBlocks, 256, 0, stream>>>(x, W1, invs, h, N);
    gather_elu_kernel<false><<<gatherBlocks, 256, 0, stream>>>(h, edge, invs, out, N);
    // Layer 2: act (sliced, d_out) -> h (sliced bf16) -> out (canonical, d_out)
    gemm_scale_kernel<true><<<gemmBlocks, 256, 0, stream>>>(out, W2, invs, h, N);
    gather_elu_kernel<true><<<gatherBlocks, 256, 0, stream>>>(h, edge, invs, out, N);
}

// Round 6
// 456.862 us; speedup vs baseline: 2.5994x; 1.0390x over previous
//
#include <hip/hip_runtime.h>
#include <hip/hip_bf16.h>
#include <math.h>

namespace {

constexpr int C = 128;       // channels
constexpr int K = 32;        // max degree
constexpr int TILE_M = 128;  // GEMM row tile
constexpr int LDSW = 132;    // LDS row stride in floats (128 + 4 pad)
constexpr int NSLICE = 8;    // channel slices == XCD count
constexpr int SLICE_C = 16;  // channels per slice (32 B bf16 rows)
constexpr int NT = 128;      // nodes per gather tile
constexpr int SW = 136;      // GEMM staging row stride (ushorts)

typedef int int4v __attribute__((ext_vector_type(4)));
typedef float float4v __attribute__((ext_vector_type(4)));
typedef unsigned short ushort8v __attribute__((ext_vector_type(8)));

__device__ __forceinline__ float bf2f(unsigned short u) {
    return __uint_as_float(((unsigned int)u) << 16);
}

// ---------------------------------------------------------------------------
// Kernel 0: invs[n] = 1/sqrt(1 + #valid neighbors). Block 0 also zeroes the
// per-slice padding row h[s][N][*] (gather's clamped index target).
// ---------------------------------------------------------------------------
__global__ __launch_bounds__(256) void deg_kernel(const int* __restrict__ edge,
                                                  float* __restrict__ invs,
                                                  unsigned int* __restrict__ hzero,
                                                  int N) {
    if (blockIdx.x == 0 && threadIdx.x < 64) {
        // 8 slices x 16 bf16 = 256 B of zeros at row N of each slice region.
        int s = threadIdx.x >> 3;
        int i = threadIdx.x & 7;
        size_t sst_u32 = (size_t)(N + 1) * SLICE_C / 2;  // uints per slice
        hzero[(size_t)s * sst_u32 + (size_t)N * SLICE_C / 2 + i] = 0u;
    }
    int t = threadIdx.x;
    int node = blockIdx.x * 8 + (t >> 5);
    int k = t & 31;
    int e = (node < N) ? edge[(size_t)node * K + k] : -1;
    unsigned long long m = __ballot(e >= 0);
    int lane = t & 63;
    unsigned int half = (lane < 32) ? (unsigned int)(m & 0xffffffffULL)
                                    : (unsigned int)(m >> 32);
    int c = __popc(half);
    if (k == 0 && node < N) invs[node] = 1.0f / sqrtf((float)(c + 1));
}

// ---------------------------------------------------------------------------
// Kernel 1: H[slice][n][c'] = bf16( (X[n] . W[ch]) * invs[n] ), ch=16*slice+c'
// fp32 vector-ALU GEMM, W in LDS (67.6 KB -> 2 blocks/CU), X from global with
// a 1-deep register prefetch. Epilogue: after the k-loop the Ws LDS is dead,
// so reuse it as a bf16 staging tile [128][SW] and write each slice with
// coalesced 16 B stores (replaces 64x 2B scattered stores per thread).
// H slice stride is (N+1) rows: row N is the gather's zero row (not written).
// ---------------------------------------------------------------------------
template <bool SLICED_IN>
__global__ __launch_bounds__(256) void gemm_scale_kernel(
    const float* __restrict__ X, const float* __restrict__ W,
    const float* __restrict__ invs, unsigned short* __restrict__ H, int N) {
    __shared__ float Ws[C * LDSW];

    const int t = threadIdx.x;
    const int n0 = blockIdx.x * TILE_M;
    const size_t in_sst = (size_t)N * SLICE_C;        // fp32 sliced input stride
    const size_t out_sst = (size_t)(N + 1) * SLICE_C; // bf16 sliced output stride

    for (int p = t; p < C * C / 4; p += 256) {
        int row = p >> 5;
        int c4 = p & 31;
        float4 v = ((const float4*)W)[p];
        *(float4*)&Ws[row * LDSW + c4 * 4] = v;
    }
    __syncthreads();

    const int tx = t & 15;  // col base: cols tx + 16*c
    const int ty = t >> 4;  // row base: rows ty + 16*r

    const float* xbase[8];
#pragma unroll
    for (int r = 0; r < 8; ++r) {
        int n = n0 + ty + r * 16;
        if (n > N - 1) n = N - 1;  // clamp; writes are guarded
        xbase[r] = X + (SLICED_IN ? (size_t)n * SLICE_C : (size_t)n * C);
    }

    float acc[8][8];
#pragma unroll
    for (int r = 0; r < 8; ++r)
#pragma unroll
        for (int c = 0; c < 8; ++c) acc[r][c] = 0.f;

    float4 a[8], an[8];
#pragma unroll
    for (int r = 0; r < 8; ++r)
        an[r] = *(const float4*)(xbase[r]);

#pragma unroll 4
    for (int i = 0; i < C; i += 4) {
#pragma unroll
        for (int r = 0; r < 8; ++r) a[r] = an[r];
        int i4 = i + 4;
        if (i4 < C) {
            size_t off = SLICED_IN ? ((size_t)(i4 >> 4) * in_sst + (i4 & 12))
                                   : (size_t)i4;
#pragma unroll
            for (int r = 0; r < 8; ++r)
                an[r] = *(const float4*)(xbase[r] + off);
        }
        float4 b[8];
#pragma unroll
        for (int c = 0; c < 8; ++c)
            b[c] = *(const float4*)&Ws[(tx + c * 16) * LDSW + i];
#pragma unroll
        for (int r = 0; r < 8; ++r)
#pragma unroll
            for (int c = 0; c < 8; ++c) {
                acc[r][c] += a[r].x * b[c].x;
                acc[r][c] += a[r].y * b[c].y;
                acc[r][c] += a[r].z * b[c].z;
                acc[r][c] += a[r].w * b[c].w;
            }
    }

    // ---- Epilogue: stage bf16 results in (dead) Ws LDS, then coalesced out.
    __syncthreads();  // all Ws reads done
    unsigned short* st = (unsigned short*)Ws;
#pragma unroll
    for (int r = 0; r < 8; ++r) {
        int n = n0 + ty + r * 16;
        float s = invs[n < N ? n : N - 1];
#pragma unroll
        for (int c = 0; c < 8; ++c) {
            __hip_bfloat16 hv = __float2bfloat16(acc[r][c] * s);
            st[(ty + r * 16) * SW + tx + 16 * c] = *(unsigned short*)&hv;
        }
    }
    __syncthreads();
    {
        const int row = t >> 1;
        const int hf = t & 1;
        const int n = n0 + row;
        if (n < N) {
#pragma unroll
            for (int s2 = 0; s2 < NSLICE; ++s2) {
                ushort8v vv = *(const ushort8v*)&st[row * SW + s2 * 16 + hf * 8];
                *(ushort8v*)(H + (size_t)s2 * out_sst + (size_t)n * SLICE_C +
                             hf * 8) = vv;
            }
        }
    }
}

// ---------------------------------------------------------------------------
// Kernel 2: channel-sliced gather + ELU, static split, UNCONDITIONAL batched
// loads. slice = blockIdx & 7 (round-robin dispatch pins each slice's blocks
// to one XCD; its 3.2 MB bf16 slice stays L2-resident — round-5 FETCH_SIZE
// confirmed). Padding index -1 is clamped to row N, a zero row, so all K=32
// loads issue unconditionally in batches of 8 -> 8 gathers in flight per wave
// (round-5 had VGPR=24 => MLP 1, latency-bound at 147 us).
// ---------------------------------------------------------------------------
template <bool CANON_OUT>
__global__ __launch_bounds__(256) void gather_elu_kernel(
    const unsigned short* __restrict__ H, const int* __restrict__ edge,
    const float* __restrict__ invs, float* __restrict__ out, int N) {
    __shared__ int idx_s[NT][33];

    const int t = threadIdx.x;
    const int s = blockIdx.x & (NSLICE - 1);
    const int grp = blockIdx.x >> 3;
    const int ngrp = 256;
    const int ntiles = (N + NT - 1) / NT;
    const size_t h_sst = (size_t)(N + 1) * SLICE_C;  // bf16 input region stride
    const size_t o_sst = (size_t)N * SLICE_C;        // fp32 sliced output stride
    const unsigned short* hs = H + (size_t)s * h_sst;
    const int nl = t >> 1;
    const int half = t & 1;

    for (int tt = grp; tt < ntiles; tt += ngrp) {
        const int base = tt * NT;

        // Stage 128 nodes' edge lists (16 KB), nontemporal coalesced loads.
#pragma unroll
        for (int ii = 0; ii < 4; ++ii) {
            int p = (ii * 256 + t) * 4;  // flat int index into NT*K
            int r = p >> 5;              // K == 32
            int c0 = p & 31;
            int node = base + r;
            int4v e = {-1, -1, -1, -1};
            if (node < N)
                e = __builtin_nontemporal_load(
                    (const int4v*)(edge + (size_t)node * K + c0));
            idx_s[r][c0 + 0] = e.x;
            idx_s[r][c0 + 1] = e.y;
            idx_s[r][c0 + 2] = e.z;
            idx_s[r][c0 + 3] = e.w;
        }
        __syncthreads();

        const int node = base + nl;
        {
            const unsigned short* hh = hs + half * 8;
            float acc[8];
#pragma unroll
            for (int i = 0; i < 8; ++i) acc[i] = 0.f;
#pragma unroll
            for (int k0 = 0; k0 < K; k0 += 8) {
                ushort8v v[8];
#pragma unroll
                for (int u = 0; u < 8; ++u) {
                    int j = idx_s[nl][k0 + u];
                    j = (j < 0) ? N : j;  // row N is all zeros
                    v[u] = *(const ushort8v*)(hh + (size_t)j * SLICE_C);
                }
#pragma unroll
                for (int u = 0; u < 8; ++u)
#pragma unroll
                    for (int i = 0; i < 8; ++i) acc[i] += bf2f(v[u][i]);
            }
            if (node < N) {
                ushort8v sv = *(const ushort8v*)(hh + (size_t)node * SLICE_C);
                float sc = invs[node];
                float r[8];
#pragma unroll
                for (int i = 0; i < 8; ++i) {
                    float x = (acc[i] + bf2f(sv[i])) * sc;
                    r[i] = x > 0.f ? x : expm1f(x);
                }
                float* dst =
                    CANON_OUT
                        ? (out + (size_t)node * C + s * SLICE_C + half * 8)
                        : (out + (size_t)s * o_sst + (size_t)node * SLICE_C +
                           half * 8);
                float4v lo = {r[0], r[1], r[2], r[3]};
                float4v hi = {r[4], r[5], r[6], r[7]};
                __builtin_nontemporal_store(lo, (float4v*)dst);
                __builtin_nontemporal_store(hi, (float4v*)(dst + 4));
            }
        }
        __syncthreads();  // idx_s reads done before next tile's staging
    }
}

}  // namespace

extern "C" void kernel_launch(void* const* d_in, const int* in_sizes, int n_in,
                              void* d_out, int out_size, void* d_ws, size_t ws_size,
                              hipStream_t stream) {
    const float* x = (const float*)d_in[0];
    const int* edge = (const int*)d_in[1];
    const float* W1 = (const float*)d_in[2];
    const float* W2 = (const float*)d_in[3];
    float* out = (float*)d_out;
    const int N = in_sizes[0] / C;  // 100000

    // Workspace: invs [N floats] | h [8 x (N+1) x 16 bf16, slice-major]
    char* ws = (char*)d_ws;
    float* invs = (float*)ws;
    size_t invs_bytes = ((size_t)N * sizeof(float) + 255) & ~(size_t)255;
    unsigned short* h = (unsigned short*)(ws + invs_bytes);

    const int nodeBlocks = (N + 7) / 8;
    const int gemmBlocks = (N + TILE_M - 1) / TILE_M;
    const int gatherBlocks = 2048;  // 256 groups x 8 slices

    deg_kernel<<<nodeBlocks, 256, 0, stream>>>(edge, invs, (unsigned int*)h, N);
    // Layer 1: x (canonical) -> h (sliced bf16) -> act (sliced fp32, in d_out)
    gemm_scale_kernel<false><<<gemmBlocks, 256, 0, stream>>>(x, W1, invs, h, N);
    gather_elu_kernel<false><<<gatherBlocks, 256, 0, stream>>>(h, edge, invs, out, N);
    // Layer 2: act (sliced, d_out) -> h (sliced bf16) -> out (canonical, d_out)
    gemm_scale_kernel<true><<<gemmBlocks, 256, 0, stream>>>(out, W2, invs, h, N);
    gather_elu_kernel<true><<<gatherBlocks, 256, 0, stream>>>(h, edge, invs, out, N);
}